// Round 1
// baseline (381.949 us; speedup 1.0000x reference)
//
#include <hip/hip_runtime.h>
#include <math.h>

#define NTOT 16384
#define NSEG 2048

// ws layout in floats
#define OFF_HH   0ull
#define OFF_XC   4194304ull
#define OFF_HC   8388608ull
#define OFF_S1H  9437184ull
#define OFF_S2H  9502720ull
#define OFF_S1O  9568256ull
#define OFF_S2O  9584640ull
#define OFF_SVAL 9601024ull   // 40 tasks * 2048
#define OFF_WN   9682944ull
#define OFF_WP   9764864ull
#define OFF_CHA  9846784ull   // 40 * 128 * 65
#define OFF_CHS  10179584ull
#define OFF_SIDX 10512384ull  // ints

// ---------------- GEMM 1: hh[16384][256] = X[16384][64] @ Wall[64][256] ----------------
// Wall[d][h*64+n] = W_heads[h][d][n]
__global__ __launch_bounds__(256) void gemm1_k(const float* __restrict__ X,
                                               const float* __restrict__ Wh,
                                               float* __restrict__ hh) {
    __shared__ float As[64][68];  // As[k][m], pad 68 keeps float4 alignment
    __shared__ float Bs[64][68];  // Bs[k][n]
    const int tid = threadIdx.x;
    const int bm = blockIdx.x, h = blockIdx.y;
    const int c0 = tid & 63, r0 = tid >> 6;
#pragma unroll
    for (int r = 0; r < 16; ++r) {
        int row = r0 + r * 4;
        As[c0][row] = X[(size_t)(bm * 64 + row) * 64 + c0];
        Bs[row][c0] = Wh[h * 4096 + row * 64 + c0];
    }
    __syncthreads();
    const int tx = tid & 15, ty = tid >> 4;
    const int m0 = ty * 4, n0 = tx * 4;
    float acc[4][4] = {};
#pragma unroll
    for (int kk = 0; kk < 64; ++kk) {
        float4 a = *(const float4*)&As[kk][m0];
        float4 b = *(const float4*)&Bs[kk][n0];
        acc[0][0] += a.x * b.x; acc[0][1] += a.x * b.y; acc[0][2] += a.x * b.z; acc[0][3] += a.x * b.w;
        acc[1][0] += a.y * b.x; acc[1][1] += a.y * b.y; acc[1][2] += a.y * b.z; acc[1][3] += a.y * b.w;
        acc[2][0] += a.z * b.x; acc[2][1] += a.z * b.y; acc[2][2] += a.z * b.z; acc[2][3] += a.z * b.w;
        acc[3][0] += a.w * b.x; acc[3][1] += a.w * b.y; acc[3][2] += a.w * b.z; acc[3][3] += a.w * b.w;
    }
#pragma unroll
    for (int i = 0; i < 4; ++i) {
        float4 v = make_float4(acc[i][0], acc[i][1], acc[i][2], acc[i][3]);
        *(float4*)&hh[(size_t)(bm * 64 + m0 + i) * 256 + h * 64 + n0] = v;
    }
}

// ---------------- GEMM 2: hc[16384][64] = XC[16384][256] @ Wo[256][64] ----------------
__global__ __launch_bounds__(256) void gemm2_k(const float* __restrict__ XC,
                                               const float* __restrict__ Wo,
                                               float* __restrict__ hc) {
    __shared__ float As[64][68];
    __shared__ float Bs[64][68];
    const int tid = threadIdx.x;
    const int bm = blockIdx.x;
    const int c0 = tid & 63, r0 = tid >> 6;
    const int tx = tid & 15, ty = tid >> 4;
    const int m0 = ty * 4, n0 = tx * 4;
    float acc[4][4] = {};
    for (int kt = 0; kt < 4; ++kt) {
#pragma unroll
        for (int r = 0; r < 16; ++r) {
            int row = r0 + r * 4;
            As[c0][row] = XC[(size_t)(bm * 64 + row) * 256 + kt * 64 + c0];
            Bs[row][c0] = Wo[(kt * 64 + row) * 64 + c0];
        }
        __syncthreads();
#pragma unroll
        for (int kk = 0; kk < 64; ++kk) {
            float4 a = *(const float4*)&As[kk][m0];
            float4 b = *(const float4*)&Bs[kk][n0];
            acc[0][0] += a.x * b.x; acc[0][1] += a.x * b.y; acc[0][2] += a.x * b.z; acc[0][3] += a.x * b.w;
            acc[1][0] += a.y * b.x; acc[1][1] += a.y * b.y; acc[1][2] += a.y * b.z; acc[1][3] += a.y * b.w;
            acc[2][0] += a.z * b.x; acc[2][1] += a.z * b.y; acc[2][2] += a.z * b.z; acc[2][3] += a.z * b.w;
            acc[3][0] += a.w * b.x; acc[3][1] += a.w * b.y; acc[3][2] += a.w * b.z; acc[3][3] += a.w * b.w;
        }
        __syncthreads();
    }
#pragma unroll
    for (int i = 0; i < 4; ++i) {
        float4 v = make_float4(acc[i][0], acc[i][1], acc[i][2], acc[i][3]);
        *(float4*)&hc[(size_t)(bm * 64 + m0 + i) * 64 + n0] = v;
    }
}

// ---------------- projections: s1/s2 per row ----------------
__global__ __launch_bounds__(256) void proj_heads_k(const float* __restrict__ hh,
                                                    const float* __restrict__ aH,
                                                    float* __restrict__ s1h,
                                                    float* __restrict__ s2h) {
    const int lane = threadIdx.x & 63;
    const int wv = threadIdx.x >> 6;
    const int n = blockIdx.x * 4 + wv;
#pragma unroll
    for (int h = 0; h < 4; ++h) {
        float v = hh[(size_t)n * 256 + h * 64 + lane];
        float p1 = v * aH[h * 128 + lane];
        float p2 = v * aH[h * 128 + 64 + lane];
#pragma unroll
        for (int off = 32; off; off >>= 1) {
            p1 += __shfl_xor(p1, off, 64);
            p2 += __shfl_xor(p2, off, 64);
        }
        if (lane == 0) { s1h[h * NTOT + n] = p1; s2h[h * NTOT + n] = p2; }
    }
}

__global__ __launch_bounds__(256) void proj_out_k(const float* __restrict__ hc,
                                                  const float* __restrict__ aO,
                                                  float* __restrict__ s1o,
                                                  float* __restrict__ s2o) {
    const int lane = threadIdx.x & 63;
    const int wv = threadIdx.x >> 6;
    const int n = blockIdx.x * 4 + wv;
    float v = hc[(size_t)n * 64 + lane];
    float p1 = v * aO[lane];
    float p2 = v * aO[64 + lane];
#pragma unroll
    for (int off = 32; off; off >>= 1) {
        p1 += __shfl_xor(p1, off, 64);
        p2 += __shfl_xor(p2, off, 64);
    }
    if (lane == 0) { s1o[n] = p1; s2o[n] = p2; }
}

// ---------------- sort + chunk prefix/suffix sums, one block per (graph,head) task ----------------
__global__ __launch_bounds__(1024) void seg_sort_k(const float* __restrict__ s2_all,
                                                   const float* __restrict__ V,
                                                   int heads, int vstride, int task0,
                                                   float* __restrict__ g_sval, int* __restrict__ g_sidx,
                                                   float* __restrict__ g_wN, float* __restrict__ g_wP,
                                                   float* __restrict__ g_chA, float* __restrict__ g_chS) {
    __shared__ float sval[NSEG];
    __shared__ int sidx[NSEG];
    __shared__ float ch[128][65];
    const int tid = threadIdx.x;
    const int t = blockIdx.x;
    const int g = t / heads, h = t % heads;
    const int gt = task0 + t;
    const float* s2p = s2_all + (size_t)h * NTOT + (size_t)g * NSEG;
    const float* Vp = V + (size_t)g * NSEG * vstride + h * 64;

    for (int i = tid; i < NSEG; i += 1024) { sval[i] = s2p[i]; sidx[i] = i; }
    __syncthreads();
    // bitonic sort ascending (value,index) pairs
    for (int k = 2; k <= NSEG; k <<= 1) {
        for (int j = k >> 1; j > 0; j >>= 1) {
#pragma unroll
            for (int rep = 0; rep < 2; ++rep) {
                int i = tid + rep * 1024;
                int ixj = i ^ j;
                if (ixj > i) {
                    float a = sval[i], b = sval[ixj];
                    bool up = ((i & k) == 0);
                    if ((a > b) == up) {
                        sval[i] = b; sval[ixj] = a;
                        int ta = sidx[i]; sidx[i] = sidx[ixj]; sidx[ixj] = ta;
                    }
                }
            }
            __syncthreads();
        }
    }
    const float M2 = sval[NSEG - 1];
    for (int i = tid; i < NSEG; i += 1024) {
        float sv = sval[i];
        float wn = __expf(0.2f * (sv - M2));   // neg-branch weight e^{alpha(s2-M2)}
        float w2 = wn * wn;
        float wp = (w2 * w2) * wn;             // pos-branch weight e^{(s2-M2)} = wn^5
        g_sval[(size_t)gt * NSEG + i] = sv;
        g_sidx[(size_t)gt * NSEG + i] = sidx[i];
        g_wN[(size_t)gt * NSEG + i] = wn;
        g_wP[(size_t)gt * NSEG + i] = wp;
        sval[i] = wn;  // sval now holds wN (own slot only; safe)
    }
    __syncthreads();
    const int d = tid & 63;
    const int cslot = tid >> 6;
    // pass 1: neg-weight chunk sums -> exclusive prefix -> g_chA
    for (int p = 0; p < 8; ++p) {
        int c = p * 16 + cslot;
        int base = c * 16;
        float sa = 0.f, swa = 0.f;
#pragma unroll
        for (int j = 0; j < 16; ++j) {
            int row = sidx[base + j];
            float wn = sval[base + j];
            float v = Vp[(size_t)row * vstride + d];
            sa += wn * v; swa += wn;
        }
        ch[c][d] = sa;
        if (d == 0) ch[c][64] = swa;
    }
    __syncthreads();
    if (tid < 65) {
        float run = 0.f;
        for (int c = 0; c < 128; ++c) { float v = ch[c][tid]; ch[c][tid] = run; run += v; }
    }
    __syncthreads();
    float* chlin = &ch[0][0];
    for (int i = tid; i < 8320; i += 1024) g_chA[(size_t)gt * 8320 + i] = chlin[i];
    __syncthreads();
    // pass 2: pos-weight chunk sums -> inclusive suffix -> g_chS
    for (int p = 0; p < 8; ++p) {
        int c = p * 16 + cslot;
        int base = c * 16;
        float ss = 0.f, sws = 0.f;
#pragma unroll
        for (int j = 0; j < 16; ++j) {
            int row = sidx[base + j];
            float wn = sval[base + j];
            float w2 = wn * wn;
            float wp = (w2 * w2) * wn;
            float v = Vp[(size_t)row * vstride + d];
            ss += wp * v; sws += wp;
        }
        ch[c][d] = ss;
        if (d == 0) ch[c][64] = sws;
    }
    __syncthreads();
    if (tid < 65) {
        float run = 0.f;
        for (int c = 127; c >= 0; --c) { run += ch[c][tid]; ch[c][tid] = run; }
    }
    __syncthreads();
    for (int i = tid; i < 8320; i += 1024) g_chS[(size_t)gt * 8320 + i] = chlin[i];
}

// ---------------- query kernel: one wave per query row, lane = feature dim ----------------
template <int MODE>  // 0: ELU -> xc ; 1: ELU + log_softmax -> out
__global__ __launch_bounds__(256) void seg_query_k(const float* __restrict__ s1_all,
                                                   const float* __restrict__ V,
                                                   float* __restrict__ out,
                                                   int heads, int vstride, int ostride, int task0,
                                                   const float* __restrict__ g_sval, const int* __restrict__ g_sidx,
                                                   const float* __restrict__ g_wN, const float* __restrict__ g_wP,
                                                   const float* __restrict__ g_chA, const float* __restrict__ g_chS) {
    __shared__ float sval[NSEG];
    __shared__ int sidx[NSEG];
    __shared__ float wN[NSEG];
    __shared__ float wP[NSEG];
    const int tid = threadIdx.x;
    const int t = blockIdx.y;
    const int g = t / heads, h = t % heads;
    const int gt = task0 + t;
    const float* s1p = s1_all + (size_t)h * NTOT + (size_t)g * NSEG;
    const float* Vp = V + (size_t)g * NSEG * vstride + h * 64;
    float* outp = out + (size_t)g * NSEG * ostride + h * 64;
    for (int i = tid; i < NSEG; i += 256) {
        sval[i] = g_sval[(size_t)gt * NSEG + i];
        sidx[i] = g_sidx[(size_t)gt * NSEG + i];
        wN[i] = g_wN[(size_t)gt * NSEG + i];
        wP[i] = g_wP[(size_t)gt * NSEG + i];
    }
    __syncthreads();
    const float M2 = sval[NSEG - 1];
    const int lane = tid & 63, wv = tid >> 6;
    const int q0 = blockIdx.x * 64;
    for (int q = q0 + wv; q < q0 + 64; q += 4) {
        float s1v = s1p[q];
        float tt = s1v + M2;
        float cc = __expf(-0.8f * fmaxf(tt, 0.f));  // e^{(alpha-1) max(t,0)}; cancels when pos-set empty
        float th = -s1v;
        int lo = 0, hi = NSEG;
        while (lo < hi) { int mid = (lo + hi) >> 1; if (sval[mid] <= th) lo = mid + 1; else hi = mid; }
        int k = lo;                                  // count of keys in neg branch
        int ck = (k >= NSEG) ? 127 : (k >> 4);
        const float* rowA = g_chA + ((size_t)gt * 128 + ck) * 65;
        float accA = rowA[lane];
        float scaA = rowA[64];
        float accS = 0.f, scaS = 0.f;
        if (ck < 127) {
            const float* rowS = g_chS + ((size_t)gt * 128 + ck + 1) * 65;
            accS = rowS[lane];
            scaS = rowS[64];
        }
        int base = ck * 16;
#pragma unroll
        for (int j = 0; j < 16; ++j) {
            int jj = base + j;
            float v = Vp[(size_t)sidx[jj] * vstride + lane];
            if (jj < k) { float w = wN[jj]; accA += w * v; scaA += w; }
            else        { float w = wP[jj]; accS += w * v; scaS += w; }
        }
        float o = (accS + cc * accA) / (scaS + cc * scaA);
        o = o > 0.f ? o : expm1f(o);  // ELU
        if (MODE == 0) {
            outp[(size_t)q * ostride + lane] = o;
        } else {
            float m = o;
#pragma unroll
            for (int off = 32; off; off >>= 1) m = fmaxf(m, __shfl_xor(m, off, 64));
            float e = __expf(o - m);
#pragma unroll
            for (int off = 32; off; off >>= 1) e += __shfl_xor(e, off, 64);
            outp[(size_t)q * ostride + lane] = o - m - __logf(e);
        }
    }
}

extern "C" void kernel_launch(void* const* d_in, const int* in_sizes, int n_in,
                              void* d_out, int out_size, void* d_ws, size_t ws_size,
                              hipStream_t stream) {
    const float* h_states = (const float*)d_in[0];
    const float* W_heads = (const float*)d_in[1];
    const float* a_heads = (const float*)d_in[2];
    const float* W_out = (const float*)d_in[3];
    const float* a_out = (const float*)d_in[4];
    float* w = (float*)d_ws;
    float* hh = w + OFF_HH;
    float* xc = w + OFF_XC;
    float* hc = w + OFF_HC;
    float* s1h = w + OFF_S1H;
    float* s2h = w + OFF_S2H;
    float* s1o = w + OFF_S1O;
    float* s2o = w + OFF_S2O;
    float* g_sval = w + OFF_SVAL;
    float* g_wN = w + OFF_WN;
    float* g_wP = w + OFF_WP;
    float* g_chA = w + OFF_CHA;
    float* g_chS = w + OFF_CHS;
    int* g_sidx = (int*)(w + OFF_SIDX);
    float* outp = (float*)d_out;

    gemm1_k<<<dim3(256, 4), 256, 0, stream>>>(h_states, W_heads, hh);
    proj_heads_k<<<4096, 256, 0, stream>>>(hh, a_heads, s1h, s2h);
    seg_sort_k<<<32, 1024, 0, stream>>>(s2h, hh, 4, 256, 0, g_sval, g_sidx, g_wN, g_wP, g_chA, g_chS);
    seg_query_k<0><<<dim3(32, 32), 256, 0, stream>>>(s1h, hh, xc, 4, 256, 256, 0,
                                                     g_sval, g_sidx, g_wN, g_wP, g_chA, g_chS);
    gemm2_k<<<256, 256, 0, stream>>>(xc, W_out, hc);
    proj_out_k<<<4096, 256, 0, stream>>>(hc, a_out, s1o, s2o);
    seg_sort_k<<<8, 1024, 0, stream>>>(s2o, hc, 1, 64, 32, g_sval, g_sidx, g_wN, g_wP, g_chA, g_chS);
    seg_query_k<1><<<dim3(32, 8), 256, 0, stream>>>(s1o, hc, outp, 1, 64, 64, 32,
                                                    g_sval, g_sidx, g_wN, g_wP, g_chA, g_chS);
}

// Round 2
// 257.274 us; speedup vs baseline: 1.4846x; 1.4846x over previous
//
#include <hip/hip_runtime.h>
#include <math.h>

#define NTOT 16384
#define NSEG 2048
#define TROW 65
#define TSTRIDE 133185ull   // 2049*65 floats per task

// ws float offsets
#define OFF_HH   0ull         // 16384*256 (hc reuses this region after query<0>)
#define OFF_XC   4194304ull   // 16384*256
#define OFF_S1H  8388608ull   // 65536
#define OFF_S2H  8454144ull   // 65536
#define OFF_S1O  8519680ull   // 16384
#define OFF_S2O  8536064ull   // 16384
#define OFF_SVAL 8552448ull   // 32*2048
#define OFF_WN   8617984ull   // 32*2048
#define OFF_CHA  8683520ull   // 32*128*65
#define OFF_CHS  8949760ull   // 32*128*65
#define OFF_SIDX 9216000ull   // 32*2048 ints
#define OFF_A    9281536ull   // 32*2049*65
#define OFF_S    13543456ull  // 32*2049*65 -> end 17805376 floats (71.2 MB)

// ---------------- GEMM 1: hh[16384][256] = X[16384][64] @ Wall[64][256] ----------------
__global__ __launch_bounds__(256) void gemm1_k(const float* __restrict__ X,
                                               const float* __restrict__ Wh,
                                               float* __restrict__ hh) {
    __shared__ float As[64][68];
    __shared__ float Bs[64][68];
    const int tid = threadIdx.x;
    const int bm = blockIdx.x, h = blockIdx.y;
    const int c0 = tid & 63, r0 = tid >> 6;
#pragma unroll
    for (int r = 0; r < 16; ++r) {
        int row = r0 + r * 4;
        As[c0][row] = X[(size_t)(bm * 64 + row) * 64 + c0];
        Bs[row][c0] = Wh[h * 4096 + row * 64 + c0];
    }
    __syncthreads();
    const int tx = tid & 15, ty = tid >> 4;
    const int m0 = ty * 4, n0 = tx * 4;
    float acc[4][4] = {};
#pragma unroll
    for (int kk = 0; kk < 64; ++kk) {
        float4 a = *(const float4*)&As[kk][m0];
        float4 b = *(const float4*)&Bs[kk][n0];
        acc[0][0] += a.x * b.x; acc[0][1] += a.x * b.y; acc[0][2] += a.x * b.z; acc[0][3] += a.x * b.w;
        acc[1][0] += a.y * b.x; acc[1][1] += a.y * b.y; acc[1][2] += a.y * b.z; acc[1][3] += a.y * b.w;
        acc[2][0] += a.z * b.x; acc[2][1] += a.z * b.y; acc[2][2] += a.z * b.z; acc[2][3] += a.z * b.w;
        acc[3][0] += a.w * b.x; acc[3][1] += a.w * b.y; acc[3][2] += a.w * b.z; acc[3][3] += a.w * b.w;
    }
#pragma unroll
    for (int i = 0; i < 4; ++i) {
        float4 v = make_float4(acc[i][0], acc[i][1], acc[i][2], acc[i][3]);
        *(float4*)&hh[(size_t)(bm * 64 + m0 + i) * 256 + h * 64 + n0] = v;
    }
}

// ---------------- GEMM 2: hc[16384][64] = XC[16384][256] @ Wo[256][64] ----------------
__global__ __launch_bounds__(256) void gemm2_k(const float* __restrict__ XC,
                                               const float* __restrict__ Wo,
                                               float* __restrict__ hc) {
    __shared__ float As[64][68];
    __shared__ float Bs[64][68];
    const int tid = threadIdx.x;
    const int bm = blockIdx.x;
    const int c0 = tid & 63, r0 = tid >> 6;
    const int tx = tid & 15, ty = tid >> 4;
    const int m0 = ty * 4, n0 = tx * 4;
    float acc[4][4] = {};
    for (int kt = 0; kt < 4; ++kt) {
#pragma unroll
        for (int r = 0; r < 16; ++r) {
            int row = r0 + r * 4;
            As[c0][row] = XC[(size_t)(bm * 64 + row) * 256 + kt * 64 + c0];
            Bs[row][c0] = Wo[(kt * 64 + row) * 64 + c0];
        }
        __syncthreads();
#pragma unroll
        for (int kk = 0; kk < 64; ++kk) {
            float4 a = *(const float4*)&As[kk][m0];
            float4 b = *(const float4*)&Bs[kk][n0];
            acc[0][0] += a.x * b.x; acc[0][1] += a.x * b.y; acc[0][2] += a.x * b.z; acc[0][3] += a.x * b.w;
            acc[1][0] += a.y * b.x; acc[1][1] += a.y * b.y; acc[1][2] += a.y * b.z; acc[1][3] += a.y * b.w;
            acc[2][0] += a.z * b.x; acc[2][1] += a.z * b.y; acc[2][2] += a.z * b.z; acc[2][3] += a.z * b.w;
            acc[3][0] += a.w * b.x; acc[3][1] += a.w * b.y; acc[3][2] += a.w * b.z; acc[3][3] += a.w * b.w;
        }
        __syncthreads();
    }
#pragma unroll
    for (int i = 0; i < 4; ++i) {
        float4 v = make_float4(acc[i][0], acc[i][1], acc[i][2], acc[i][3]);
        *(float4*)&hc[(size_t)(bm * 64 + m0 + i) * 64 + n0] = v;
    }
}

// ---------------- projections ----------------
__global__ __launch_bounds__(256) void proj_heads_k(const float* __restrict__ hh,
                                                    const float* __restrict__ aH,
                                                    float* __restrict__ s1h,
                                                    float* __restrict__ s2h) {
    const int lane = threadIdx.x & 63;
    const int wv = threadIdx.x >> 6;
    const int n = blockIdx.x * 4 + wv;
#pragma unroll
    for (int h = 0; h < 4; ++h) {
        float v = hh[(size_t)n * 256 + h * 64 + lane];
        float p1 = v * aH[h * 128 + lane];
        float p2 = v * aH[h * 128 + 64 + lane];
#pragma unroll
        for (int off = 32; off; off >>= 1) {
            p1 += __shfl_xor(p1, off, 64);
            p2 += __shfl_xor(p2, off, 64);
        }
        if (lane == 0) { s1h[h * NTOT + n] = p1; s2h[h * NTOT + n] = p2; }
    }
}

__global__ __launch_bounds__(256) void proj_out_k(const float* __restrict__ hc,
                                                  const float* __restrict__ aO,
                                                  float* __restrict__ s1o,
                                                  float* __restrict__ s2o) {
    const int lane = threadIdx.x & 63;
    const int wv = threadIdx.x >> 6;
    const int n = blockIdx.x * 4 + wv;
    float v = hc[(size_t)n * 64 + lane];
    float p1 = v * aO[lane];
    float p2 = v * aO[64 + lane];
#pragma unroll
    for (int off = 32; off; off >>= 1) {
        p1 += __shfl_xor(p1, off, 64);
        p2 += __shfl_xor(p2, off, 64);
    }
    if (lane == 0) { s1o[n] = p1; s2o[n] = p2; }
}

// ---------------- sort + chunk sums/scans; one block per (graph,head) task ----------------
__global__ __launch_bounds__(1024) void seg_sort_k(const float* __restrict__ s2_all,
                                                   const float* __restrict__ V,
                                                   int heads, int vstride,
                                                   float* __restrict__ g_sval, int* __restrict__ g_sidx,
                                                   float* __restrict__ g_wN,
                                                   float* __restrict__ g_chA, float* __restrict__ g_chS,
                                                   float* __restrict__ g_A, float* __restrict__ g_S) {
    __shared__ float sval[NSEG];
    __shared__ int sidx[NSEG];
    __shared__ float chA[128][65];
    __shared__ float chS[128][65];
    const int tid = threadIdx.x;
    const int t = blockIdx.x;
    const int g = t / heads, h = t % heads;
    const float* s2p = s2_all + (size_t)h * NTOT + (size_t)g * NSEG;
    const float* Vp = V + (size_t)g * NSEG * vstride + h * 64;

    for (int i = tid; i < NSEG; i += 1024) { sval[i] = s2p[i]; sidx[i] = i; }
    __syncthreads();
    for (int k = 2; k <= NSEG; k <<= 1) {
        for (int j = k >> 1; j > 0; j >>= 1) {
#pragma unroll
            for (int rep = 0; rep < 2; ++rep) {
                int i = tid + rep * 1024;
                int ixj = i ^ j;
                if (ixj > i) {
                    float a = sval[i], b = sval[ixj];
                    bool up = ((i & k) == 0);
                    if ((a > b) == up) {
                        sval[i] = b; sval[ixj] = a;
                        int ta = sidx[i]; sidx[i] = sidx[ixj]; sidx[ixj] = ta;
                    }
                }
            }
            __syncthreads();
        }
    }
    const float M2 = sval[NSEG - 1];
    __syncthreads();  // all threads must read M2 before sval is overwritten with weights
    for (int i = tid; i < NSEG; i += 1024) {
        float sv = sval[i];
        float wn = __expf(0.2f * (sv - M2));
        g_sval[(size_t)t * NSEG + i] = sv;
        g_sidx[(size_t)t * NSEG + i] = sidx[i];
        g_wN[(size_t)t * NSEG + i] = wn;
        sval[i] = wn;
    }
    __syncthreads();
    const int d = tid & 63, cs = tid >> 6;
    for (int p = 0; p < 8; ++p) {
        int c = p * 16 + cs, base = c * 16;
        float sa = 0.f, swa = 0.f, ss = 0.f, sws = 0.f;
#pragma unroll
        for (int j = 0; j < 16; ++j) {
            float wn = sval[base + j];
            float w2 = wn * wn, wp = w2 * w2 * wn;
            float v = Vp[(size_t)sidx[base + j] * vstride + d];
            sa += wn * v; swa += wn;
            ss += wp * v; sws += wp;
        }
        chA[c][d] = sa; chS[c][d] = ss;
        if (d == 0) { chA[c][64] = swa; chS[c][64] = sws; }
    }
    __syncthreads();
    if (tid < 65) {  // exclusive prefix of chunk sums (A); also write total row A[2048]
        float run = 0.f;
        for (int c = 0; c < 128; ++c) { float v = chA[c][tid]; chA[c][tid] = run; run += v; }
        g_A[(size_t)t * TSTRIDE + (size_t)2048 * TROW + tid] = run;
    }
    if (tid >= 512 && tid < 577) {  // inclusive suffix of chunk sums (S); write zero row S[2048]
        int l = tid - 512;
        float run = 0.f;
        for (int c = 127; c >= 0; --c) { run += chS[c][l]; chS[c][l] = run; }
        g_S[(size_t)t * TSTRIDE + (size_t)2048 * TROW + l] = 0.f;
    }
    __syncthreads();
    const float* a0 = &chA[0][0];
    const float* s0 = &chS[0][0];
    for (int i = tid; i < 8320; i += 1024) {
        g_chA[(size_t)t * 8320 + i] = a0[i];
        g_chS[(size_t)t * 8320 + i] = s0[i];
    }
}

// ---------------- positional prefix/suffix table build: 1 wave per chunk ----------------
__global__ __launch_bounds__(256) void seg_tab_k(const float* __restrict__ V,
                                                 int heads, int vstride,
                                                 const int* __restrict__ g_sidx,
                                                 const float* __restrict__ g_wN,
                                                 const float* __restrict__ g_chA,
                                                 const float* __restrict__ g_chS,
                                                 float* __restrict__ g_A, float* __restrict__ g_S) {
    const int t = blockIdx.y, g = t / heads, h = t % heads;
    const int wv = threadIdx.x >> 6, lane = threadIdx.x & 63;
    const int c = blockIdx.x * 4 + wv;
    const int base = c * 16;
    const float* Vp = V + (size_t)g * NSEG * vstride + h * 64;
    const int* sidx = g_sidx + (size_t)t * NSEG + base;
    const float* wnp = g_wN + (size_t)t * NSEG + base;
    float wn[16], vv[16];
#pragma unroll
    for (int j = 0; j < 16; ++j) wn[j] = wnp[j];
#pragma unroll
    for (int j = 0; j < 16; ++j) vv[j] = Vp[(size_t)sidx[j] * vstride + lane];
    float* A = g_A + (size_t)t * TSTRIDE;
    float* S = g_S + (size_t)t * TSTRIDE;
    float accA = g_chA[((size_t)t * 128 + c) * TROW + lane];
    float scaA = g_chA[((size_t)t * 128 + c) * TROW + 64];
#pragma unroll
    for (int j = 0; j < 16; ++j) {
        size_t pos = base + j;
        A[pos * TROW + lane] = accA;
        if (lane == 0) A[pos * TROW + 64] = scaA;
        accA += wn[j] * vv[j]; scaA += wn[j];
    }
    float accS = 0.f, scaS = 0.f;
    if (c < 127) {
        accS = g_chS[((size_t)t * 128 + c + 1) * TROW + lane];
        scaS = g_chS[((size_t)t * 128 + c + 1) * TROW + 64];
    }
#pragma unroll
    for (int j = 15; j >= 0; --j) {
        float w = wn[j], w2 = w * w, wp = w2 * w2 * w;
        accS += wp * vv[j]; scaS += wp;
        size_t pos = base + j;
        S[pos * TROW + lane] = accS;
        if (lane == 0) S[pos * TROW + 64] = scaS;
    }
}

// ---------------- query: binary search + 2 table-row reads per query ----------------
template <int MODE>  // 0: ELU -> xc ; 1: ELU + log_softmax -> out
__global__ __launch_bounds__(256) void seg_query_k(const float* __restrict__ s1_all,
                                                   float* __restrict__ out,
                                                   int heads, int ostride,
                                                   const float* __restrict__ g_sval,
                                                   const float* __restrict__ g_A,
                                                   const float* __restrict__ g_S) {
    __shared__ float sval[NSEG];
    const int tid = threadIdx.x;
    const int t = blockIdx.y, g = t / heads, h = t % heads;
    const float4* sv4 = (const float4*)(g_sval + (size_t)t * NSEG);
    for (int i = tid; i < NSEG / 4; i += 256) ((float4*)sval)[i] = sv4[i];
    __syncthreads();
    const float M2 = sval[NSEG - 1];
    const int lane = tid & 63, wv = tid >> 6;
    const int q0 = blockIdx.x * 128 + wv * 32;
    const float* s1p = s1_all + (size_t)h * NTOT + (size_t)g * NSEG;
    float* outp = out + (size_t)g * NSEG * ostride + h * 64;
    const float* A = g_A + (size_t)t * TSTRIDE;
    const float* S = g_S + (size_t)t * TSTRIDE;
    // lane-parallel binary search: lane l (and l+32) searches query q0+l
    int myq = q0 + (lane & 31);
    float s1v = s1p[myq];
    float th = -s1v;
    int lo = 0, hi = NSEG;
    while (lo < hi) { int mid = (lo + hi) >> 1; if (sval[mid] <= th) lo = mid + 1; else hi = mid; }
    for (int j = 0; j < 32; ++j) {
        int k = __shfl(lo, j, 64);
        float s1q = __shfl(s1v, j, 64);
        const float* rowA = A + (size_t)k * TROW;
        const float* rowS = S + (size_t)k * TROW;
        float accA = rowA[lane], scaA = rowA[64];
        float accS = rowS[lane], scaS = rowS[64];
        float cc = __expf(-0.8f * fmaxf(s1q + M2, 0.f));  // exact: pos-set empty when s1q+M2<0
        float o = (accS + cc * accA) / (scaS + cc * scaA);
        o = o > 0.f ? o : expm1f(o);  // ELU
        int q = q0 + j;
        if (MODE == 0) {
            outp[(size_t)q * ostride + lane] = o;
        } else {
            float m = o;
#pragma unroll
            for (int off = 32; off; off >>= 1) m = fmaxf(m, __shfl_xor(m, off, 64));
            float e = __expf(o - m);
#pragma unroll
            for (int off = 32; off; off >>= 1) e += __shfl_xor(e, off, 64);
            outp[(size_t)q * ostride + lane] = o - m - __logf(e);
        }
    }
}

extern "C" void kernel_launch(void* const* d_in, const int* in_sizes, int n_in,
                              void* d_out, int out_size, void* d_ws, size_t ws_size,
                              hipStream_t stream) {
    const float* h_states = (const float*)d_in[0];
    const float* W_heads = (const float*)d_in[1];
    const float* a_heads = (const float*)d_in[2];
    const float* W_out = (const float*)d_in[3];
    const float* a_out = (const float*)d_in[4];
    float* w = (float*)d_ws;
    float* hh = w + OFF_HH;
    float* xc = w + OFF_XC;
    float* hc = w + OFF_HH;  // reuse: hh dead after seg_query<0>
    float* s1h = w + OFF_S1H;
    float* s2h = w + OFF_S2H;
    float* s1o = w + OFF_S1O;
    float* s2o = w + OFF_S2O;
    float* g_sval = w + OFF_SVAL;
    float* g_wN = w + OFF_WN;
    float* g_chA = w + OFF_CHA;
    float* g_chS = w + OFF_CHS;
    int* g_sidx = (int*)(w + OFF_SIDX);
    float* g_A = w + OFF_A;
    float* g_S = w + OFF_S;
    float* outp = (float*)d_out;

    gemm1_k<<<dim3(256, 4), 256, 0, stream>>>(h_states, W_heads, hh);
    proj_heads_k<<<4096, 256, 0, stream>>>(hh, a_heads, s1h, s2h);
    seg_sort_k<<<32, 1024, 0, stream>>>(s2h, hh, 4, 256, g_sval, g_sidx, g_wN, g_chA, g_chS, g_A, g_S);
    seg_tab_k<<<dim3(32, 32), 256, 0, stream>>>(hh, 4, 256, g_sidx, g_wN, g_chA, g_chS, g_A, g_S);
    seg_query_k<0><<<dim3(16, 32), 256, 0, stream>>>(s1h, xc, 4, 256, g_sval, g_A, g_S);
    gemm2_k<<<256, 256, 0, stream>>>(xc, W_out, hc);
    proj_out_k<<<4096, 256, 0, stream>>>(hc, a_out, s1o, s2o);
    seg_sort_k<<<8, 1024, 0, stream>>>(s2o, hc, 1, 64, g_sval, g_sidx, g_wN, g_chA, g_chS, g_A, g_S);
    seg_tab_k<<<dim3(32, 8), 256, 0, stream>>>(hc, 1, 64, g_sidx, g_wN, g_chA, g_chS, g_A, g_S);
    seg_query_k<1><<<dim3(16, 8), 256, 0, stream>>>(s1o, outp, 1, 64, g_sval, g_A, g_S);
}

// Round 3
// 211.431 us; speedup vs baseline: 1.8065x; 1.2168x over previous
//
#include <hip/hip_runtime.h>
#include <math.h>

#define NTOT 16384
#define NSEG 2048
#define TROW 65
#define TSTRIDE 133185ull   // 2049*65 floats per task

// ws float offsets
#define OFF_HH   0ull         // 16384*256 (hc reuses this region after query<0>)
#define OFF_XC   4194304ull   // 16384*256
#define OFF_S1H  8388608ull   // 65536
#define OFF_S2H  8454144ull   // 65536
#define OFF_S1O  8519680ull   // 16384
#define OFF_S2O  8536064ull   // 16384
#define OFF_SVAL 8552448ull   // 32*2048
#define OFF_WN   8617984ull   // 32*2048
#define OFF_CHA  8683520ull   // 32*128*65
#define OFF_CHS  8949760ull   // 32*128*65
#define OFF_SIDX 9216000ull   // 32*2048 ints
#define OFF_A    9281536ull   // 32*2049*65
#define OFF_S    13543456ull  // 32*2049*65 -> end 17805376 floats (71.2 MB)

__device__ inline unsigned long long pack_key(float v, int idx) {
    unsigned u = __float_as_uint(v);
    u = (u & 0x80000000u) ? ~u : (u | 0x80000000u);
    return ((unsigned long long)u << 32) | (unsigned)idx;
}
__device__ inline float unpack_key(unsigned long long k) {
    unsigned u = (unsigned)(k >> 32);
    u = (u & 0x80000000u) ? (u ^ 0x80000000u) : ~u;
    return __uint_as_float(u);
}
__device__ inline unsigned long long shfl_xor_u64(unsigned long long x, int mask) {
    unsigned lo = (unsigned)x, hi = (unsigned)(x >> 32);
    lo = (unsigned)__shfl_xor((int)lo, mask, 64);
    hi = (unsigned)__shfl_xor((int)hi, mask, 64);
    return ((unsigned long long)hi << 32) | lo;
}

// ---------------- GEMM 1 + fused s1/s2 projection ----------------
__global__ __launch_bounds__(256) void gemm1_k(const float* __restrict__ X,
                                               const float* __restrict__ Wh,
                                               const float* __restrict__ aH,
                                               float* __restrict__ hh,
                                               float* __restrict__ s1h,
                                               float* __restrict__ s2h) {
    __shared__ float As[64][68];
    __shared__ float Bs[64][68];
    const int tid = threadIdx.x;
    const int bm = blockIdx.x, h = blockIdx.y;
    const int c0 = tid & 63, r0 = tid >> 6;
#pragma unroll
    for (int r = 0; r < 16; ++r) {
        int row = r0 + r * 4;
        As[c0][row] = X[(size_t)(bm * 64 + row) * 64 + c0];
        Bs[row][c0] = Wh[h * 4096 + row * 64 + c0];
    }
    __syncthreads();
    const int tx = tid & 15, ty = tid >> 4;
    const int m0 = ty * 4, n0 = tx * 4;
    float acc[4][4] = {};
#pragma unroll
    for (int kk = 0; kk < 64; ++kk) {
        float4 a = *(const float4*)&As[kk][m0];
        float4 b = *(const float4*)&Bs[kk][n0];
        acc[0][0] += a.x * b.x; acc[0][1] += a.x * b.y; acc[0][2] += a.x * b.z; acc[0][3] += a.x * b.w;
        acc[1][0] += a.y * b.x; acc[1][1] += a.y * b.y; acc[1][2] += a.y * b.z; acc[1][3] += a.y * b.w;
        acc[2][0] += a.z * b.x; acc[2][1] += a.z * b.y; acc[2][2] += a.z * b.z; acc[2][3] += a.z * b.w;
        acc[3][0] += a.w * b.x; acc[3][1] += a.w * b.y; acc[3][2] += a.w * b.z; acc[3][3] += a.w * b.w;
    }
#pragma unroll
    for (int i = 0; i < 4; ++i) {
        float4 v = make_float4(acc[i][0], acc[i][1], acc[i][2], acc[i][3]);
        *(float4*)&hh[(size_t)(bm * 64 + m0 + i) * 256 + h * 64 + n0] = v;
    }
    // fused projection: row r gets s1 = hh_row . aH[h][0:64], s2 = hh_row . aH[h][64:128]
#pragma unroll
    for (int i = 0; i < 4; ++i) {
        float p1 = 0.f, p2 = 0.f;
#pragma unroll
        for (int jj = 0; jj < 4; ++jj) {
            p1 += acc[i][jj] * aH[h * 128 + n0 + jj];
            p2 += acc[i][jj] * aH[h * 128 + 64 + n0 + jj];
        }
#pragma unroll
        for (int off = 8; off; off >>= 1) {
            p1 += __shfl_xor(p1, off, 16);
            p2 += __shfl_xor(p2, off, 16);
        }
        if (tx == 0) {
            s1h[h * NTOT + bm * 64 + m0 + i] = p1;
            s2h[h * NTOT + bm * 64 + m0 + i] = p2;
        }
    }
}

// ---------------- GEMM 2 + fused s1/s2 projection ----------------
__global__ __launch_bounds__(256) void gemm2_k(const float* __restrict__ XC,
                                               const float* __restrict__ Wo,
                                               const float* __restrict__ aO,
                                               float* __restrict__ hc,
                                               float* __restrict__ s1o,
                                               float* __restrict__ s2o) {
    __shared__ float As[64][68];
    __shared__ float Bs[64][68];
    const int tid = threadIdx.x;
    const int bm = blockIdx.x;
    const int c0 = tid & 63, r0 = tid >> 6;
    const int tx = tid & 15, ty = tid >> 4;
    const int m0 = ty * 4, n0 = tx * 4;
    float acc[4][4] = {};
    for (int kt = 0; kt < 4; ++kt) {
#pragma unroll
        for (int r = 0; r < 16; ++r) {
            int row = r0 + r * 4;
            As[c0][row] = XC[(size_t)(bm * 64 + row) * 256 + kt * 64 + c0];
            Bs[row][c0] = Wo[(kt * 64 + row) * 64 + c0];
        }
        __syncthreads();
#pragma unroll
        for (int kk = 0; kk < 64; ++kk) {
            float4 a = *(const float4*)&As[kk][m0];
            float4 b = *(const float4*)&Bs[kk][n0];
            acc[0][0] += a.x * b.x; acc[0][1] += a.x * b.y; acc[0][2] += a.x * b.z; acc[0][3] += a.x * b.w;
            acc[1][0] += a.y * b.x; acc[1][1] += a.y * b.y; acc[1][2] += a.y * b.z; acc[1][3] += a.y * b.w;
            acc[2][0] += a.z * b.x; acc[2][1] += a.z * b.y; acc[2][2] += a.z * b.z; acc[2][3] += a.z * b.w;
            acc[3][0] += a.w * b.x; acc[3][1] += a.w * b.y; acc[3][2] += a.w * b.z; acc[3][3] += a.w * b.w;
        }
        __syncthreads();
    }
#pragma unroll
    for (int i = 0; i < 4; ++i) {
        float4 v = make_float4(acc[i][0], acc[i][1], acc[i][2], acc[i][3]);
        *(float4*)&hc[(size_t)(bm * 64 + m0 + i) * 64 + n0] = v;
    }
#pragma unroll
    for (int i = 0; i < 4; ++i) {
        float p1 = 0.f, p2 = 0.f;
#pragma unroll
        for (int jj = 0; jj < 4; ++jj) {
            p1 += acc[i][jj] * aO[n0 + jj];
            p2 += acc[i][jj] * aO[64 + n0 + jj];
        }
#pragma unroll
        for (int off = 8; off; off >>= 1) {
            p1 += __shfl_xor(p1, off, 16);
            p2 += __shfl_xor(p2, off, 16);
        }
        if (tx == 0) {
            s1o[bm * 64 + m0 + i] = p1;
            s2o[bm * 64 + m0 + i] = p2;
        }
    }
}

// ---------------- sort only: hybrid register/shuffle/LDS bitonic on packed u64 ----------------
__global__ __launch_bounds__(1024) void sort_k(const float* __restrict__ s2_all, int heads,
                                               float* __restrict__ g_sval, int* __restrict__ g_sidx,
                                               float* __restrict__ g_wN) {
    __shared__ unsigned long long sA[1024];
    __shared__ unsigned long long sB[1024];
    __shared__ float sM2;
    const int tid = threadIdx.x, t = blockIdx.x;
    const int g = t / heads, h = t % heads;
    const float* s2p = s2_all + (size_t)h * NTOT + (size_t)g * NSEG;
    unsigned long long a0 = pack_key(s2p[tid], tid);
    unsigned long long a1 = pack_key(s2p[tid + 1024], tid + 1024);
    for (int k = 2; k <= 2048; k <<= 1) {
        const bool up0 = (tid & k) == 0;
        const bool up1 = (((tid + 1024) & k) == 0);
        for (int j = k >> 1; j > 0; j >>= 1) {
            if (j >= 1024) {
                unsigned long long lo = a0 < a1 ? a0 : a1;
                unsigned long long hi = a0 < a1 ? a1 : a0;
                a0 = up0 ? lo : hi;
                a1 = up0 ? hi : lo;
            } else if (j >= 64) {
                __syncthreads();
                sA[tid] = a0; sB[tid] = a1;
                __syncthreads();
                unsigned long long p0 = sA[tid ^ j], p1 = sB[tid ^ j];
                bool lower = (tid & j) == 0;
                a0 = ((a0 < p0) == (lower == up0)) ? a0 : p0;
                a1 = ((a1 < p1) == (lower == up1)) ? a1 : p1;
            } else {
                unsigned long long p0 = shfl_xor_u64(a0, j);
                unsigned long long p1 = shfl_xor_u64(a1, j);
                bool lower = (tid & j) == 0;
                a0 = ((a0 < p0) == (lower == up0)) ? a0 : p0;
                a1 = ((a1 < p1) == (lower == up1)) ? a1 : p1;
            }
        }
    }
    float v0 = unpack_key(a0), v1 = unpack_key(a1);
    if (tid == 1023) sM2 = v1;
    __syncthreads();
    const float M2 = sM2;
    size_t o = (size_t)t * NSEG;
    g_sval[o + tid] = v0;
    g_sval[o + tid + 1024] = v1;
    g_sidx[o + tid] = (int)(unsigned)(a0 & 0xffffffffu);
    g_sidx[o + tid + 1024] = (int)(unsigned)(a1 & 0xffffffffu);
    g_wN[o + tid] = __expf(0.2f * (v0 - M2));
    g_wN[o + tid + 1024] = __expf(0.2f * (v1 - M2));
}

// ---------------- raw chunk sums: one wave per 16-element chunk, machine-wide ----------------
__global__ __launch_bounds__(256) void chunks_k(const float* __restrict__ V,
                                                int heads, int vstride,
                                                const int* __restrict__ g_sidx,
                                                const float* __restrict__ g_wN,
                                                float* __restrict__ g_chA, float* __restrict__ g_chS) {
    const int t = blockIdx.y, g = t / heads, h = t % heads;
    const int wv = threadIdx.x >> 6, lane = threadIdx.x & 63;
    const int c = blockIdx.x * 4 + wv, base = c * 16;
    const float* Vp = V + (size_t)g * NSEG * vstride + h * 64;
    float wn_l = 0.f; int si_l = 0;
    if (lane < 16) {
        wn_l = g_wN[(size_t)t * NSEG + base + lane];
        si_l = g_sidx[(size_t)t * NSEG + base + lane];
    }
    float sa = 0.f, swa = 0.f, ss = 0.f, sws = 0.f;
#pragma unroll
    for (int j = 0; j < 16; ++j) {
        float wn = __shfl(wn_l, j, 64);
        int row = __shfl(si_l, j, 64);
        float v = Vp[(size_t)row * vstride + lane];
        float w2 = wn * wn, wp = w2 * w2 * wn;
        sa += wn * v; swa += wn;
        ss += wp * v; sws += wp;
    }
    size_t o = ((size_t)t * 128 + c) * TROW;
    g_chA[o + lane] = sa;
    g_chS[o + lane] = ss;
    if (lane == 0) { g_chA[o + 64] = swa; g_chS[o + 64] = sws; }
}

// ---------------- per-task chunk scans (in place) + boundary table rows ----------------
__global__ __launch_bounds__(256) void scan_k(float* __restrict__ g_chA, float* __restrict__ g_chS,
                                              float* __restrict__ g_A, float* __restrict__ g_S) {
    __shared__ float M[128 * 65];
    const int t = blockIdx.x, tid = threadIdx.x;
    for (int i = tid; i < 8320; i += 256) M[i] = g_chA[(size_t)t * 8320 + i];
    __syncthreads();
    if (tid < 65) {  // exclusive prefix over chunks
        float run = 0.f;
        for (int c = 0; c < 128; ++c) { float v = M[c * 65 + tid]; M[c * 65 + tid] = run; run += v; }
        g_A[(size_t)t * TSTRIDE + (size_t)2048 * TROW + tid] = run;  // total row (k=2048)
    }
    __syncthreads();
    for (int i = tid; i < 8320; i += 256) g_chA[(size_t)t * 8320 + i] = M[i];
    __syncthreads();
    for (int i = tid; i < 8320; i += 256) M[i] = g_chS[(size_t)t * 8320 + i];
    __syncthreads();
    if (tid < 65) {  // inclusive suffix over chunks
        float run = 0.f;
        for (int c = 127; c >= 0; --c) { run += M[c * 65 + tid]; M[c * 65 + tid] = run; }
        g_S[(size_t)t * TSTRIDE + (size_t)2048 * TROW + tid] = 0.f;  // empty-suffix row
    }
    __syncthreads();
    for (int i = tid; i < 8320; i += 256) g_chS[(size_t)t * 8320 + i] = M[i];
}

// ---------------- positional prefix/suffix table build: 1 wave per chunk ----------------
__global__ __launch_bounds__(256) void seg_tab_k(const float* __restrict__ V,
                                                 int heads, int vstride,
                                                 const int* __restrict__ g_sidx,
                                                 const float* __restrict__ g_wN,
                                                 const float* __restrict__ g_chA,
                                                 const float* __restrict__ g_chS,
                                                 float* __restrict__ g_A, float* __restrict__ g_S) {
    const int t = blockIdx.y, g = t / heads, h = t % heads;
    const int wv = threadIdx.x >> 6, lane = threadIdx.x & 63;
    const int c = blockIdx.x * 4 + wv;
    const int base = c * 16;
    const float* Vp = V + (size_t)g * NSEG * vstride + h * 64;
    const int* sidx = g_sidx + (size_t)t * NSEG + base;
    const float* wnp = g_wN + (size_t)t * NSEG + base;
    float wn[16], vv[16];
#pragma unroll
    for (int j = 0; j < 16; ++j) wn[j] = wnp[j];
#pragma unroll
    for (int j = 0; j < 16; ++j) vv[j] = Vp[(size_t)sidx[j] * vstride + lane];
    float* A = g_A + (size_t)t * TSTRIDE;
    float* S = g_S + (size_t)t * TSTRIDE;
    float accA = g_chA[((size_t)t * 128 + c) * TROW + lane];
    float scaA = g_chA[((size_t)t * 128 + c) * TROW + 64];
#pragma unroll
    for (int j = 0; j < 16; ++j) {
        size_t pos = base + j;
        A[pos * TROW + lane] = accA;
        if (lane == 0) A[pos * TROW + 64] = scaA;
        accA += wn[j] * vv[j]; scaA += wn[j];
    }
    float accS = 0.f, scaS = 0.f;
    if (c < 127) {
        accS = g_chS[((size_t)t * 128 + c + 1) * TROW + lane];
        scaS = g_chS[((size_t)t * 128 + c + 1) * TROW + 64];
    }
#pragma unroll
    for (int j = 15; j >= 0; --j) {
        float w = wn[j], w2 = w * w, wp = w2 * w2 * w;
        accS += wp * vv[j]; scaS += wp;
        size_t pos = base + j;
        S[pos * TROW + lane] = accS;
        if (lane == 0) S[pos * TROW + 64] = scaS;
    }
}

// ---------------- query: binary search + 2 table-row reads per query ----------------
template <int MODE>  // 0: ELU -> xc ; 1: ELU + log_softmax -> out
__global__ __launch_bounds__(256) void seg_query_k(const float* __restrict__ s1_all,
                                                   float* __restrict__ out,
                                                   int heads, int ostride,
                                                   const float* __restrict__ g_sval,
                                                   const float* __restrict__ g_A,
                                                   const float* __restrict__ g_S) {
    __shared__ float sval[NSEG];
    const int tid = threadIdx.x;
    const int t = blockIdx.y, g = t / heads, h = t % heads;
    const float4* sv4 = (const float4*)(g_sval + (size_t)t * NSEG);
    for (int i = tid; i < NSEG / 4; i += 256) ((float4*)sval)[i] = sv4[i];
    __syncthreads();
    const float M2 = sval[NSEG - 1];
    const int lane = tid & 63, wv = tid >> 6;
    const int q0 = blockIdx.x * 128 + wv * 32;
    const float* s1p = s1_all + (size_t)h * NTOT + (size_t)g * NSEG;
    float* outp = out + (size_t)g * NSEG * ostride + h * 64;
    const float* A = g_A + (size_t)t * TSTRIDE;
    const float* S = g_S + (size_t)t * TSTRIDE;
    int myq = q0 + (lane & 31);
    float s1v = s1p[myq];
    float th = -s1v;
    int lo = 0, hi = NSEG;
    while (lo < hi) { int mid = (lo + hi) >> 1; if (sval[mid] <= th) lo = mid + 1; else hi = mid; }
    for (int j = 0; j < 32; ++j) {
        int k = __shfl(lo, j, 64);
        float s1q = __shfl(s1v, j, 64);
        const float* rowA = A + (size_t)k * TROW;
        const float* rowS = S + (size_t)k * TROW;
        float accA = rowA[lane], scaA = rowA[64];
        float accS = rowS[lane], scaS = rowS[64];
        float cc = __expf(-0.8f * fmaxf(s1q + M2, 0.f));
        float o = (accS + cc * accA) / (scaS + cc * scaA);
        o = o > 0.f ? o : expm1f(o);  // ELU
        int q = q0 + j;
        if (MODE == 0) {
            outp[(size_t)q * ostride + lane] = o;
        } else {
            float m = o;
#pragma unroll
            for (int off = 32; off; off >>= 1) m = fmaxf(m, __shfl_xor(m, off, 64));
            float e = __expf(o - m);
#pragma unroll
            for (int off = 32; off; off >>= 1) e += __shfl_xor(e, off, 64);
            outp[(size_t)q * ostride + lane] = o - m - __logf(e);
        }
    }
}

extern "C" void kernel_launch(void* const* d_in, const int* in_sizes, int n_in,
                              void* d_out, int out_size, void* d_ws, size_t ws_size,
                              hipStream_t stream) {
    const float* h_states = (const float*)d_in[0];
    const float* W_heads = (const float*)d_in[1];
    const float* a_heads = (const float*)d_in[2];
    const float* W_out = (const float*)d_in[3];
    const float* a_out = (const float*)d_in[4];
    float* w = (float*)d_ws;
    float* hh = w + OFF_HH;
    float* xc = w + OFF_XC;
    float* hc = w + OFF_HH;  // reuse: hh dead after seg_tab (head layer)
    float* s1h = w + OFF_S1H;
    float* s2h = w + OFF_S2H;
    float* s1o = w + OFF_S1O;
    float* s2o = w + OFF_S2O;
    float* g_sval = w + OFF_SVAL;
    float* g_wN = w + OFF_WN;
    float* g_chA = w + OFF_CHA;
    float* g_chS = w + OFF_CHS;
    int* g_sidx = (int*)(w + OFF_SIDX);
    float* g_A = w + OFF_A;
    float* g_S = w + OFF_S;
    float* outp = (float*)d_out;

    gemm1_k<<<dim3(256, 4), 256, 0, stream>>>(h_states, W_heads, a_heads, hh, s1h, s2h);
    sort_k<<<32, 1024, 0, stream>>>(s2h, 4, g_sval, g_sidx, g_wN);
    chunks_k<<<dim3(32, 32), 256, 0, stream>>>(hh, 4, 256, g_sidx, g_wN, g_chA, g_chS);
    scan_k<<<32, 256, 0, stream>>>(g_chA, g_chS, g_A, g_S);
    seg_tab_k<<<dim3(32, 32), 256, 0, stream>>>(hh, 4, 256, g_sidx, g_wN, g_chA, g_chS, g_A, g_S);
    seg_query_k<0><<<dim3(16, 32), 256, 0, stream>>>(s1h, xc, 4, 256, g_sval, g_A, g_S);
    gemm2_k<<<256, 256, 0, stream>>>(xc, W_out, a_out, hc, s1o, s2o);
    sort_k<<<8, 1024, 0, stream>>>(s2o, 1, g_sval, g_sidx, g_wN);
    chunks_k<<<dim3(32, 8), 256, 0, stream>>>(hc, 1, 64, g_sidx, g_wN, g_chA, g_chS);
    scan_k<<<8, 256, 0, stream>>>(g_chA, g_chS, g_A, g_S);
    seg_tab_k<<<dim3(32, 8), 256, 0, stream>>>(hc, 1, 64, g_sidx, g_wN, g_chA, g_chS, g_A, g_S);
    seg_query_k<1><<<dim3(16, 8), 256, 0, stream>>>(s1o, outp, 1, 64, g_sval, g_A, g_S);
}

// Round 4
// 203.705 us; speedup vs baseline: 1.8750x; 1.0379x over previous
//
#include <hip/hip_runtime.h>
#include <math.h>

#define NTOT 16384
#define NSEG 2048
#define TROW 65
#define TSTRIDE 133185ull   // 2049*65 floats per task

// ws float offsets
#define OFF_HH   0ull         // 16384*256 (hc reuses this region)
#define OFF_XC   4194304ull   // 16384*256
#define OFF_S1H  8388608ull   // 65536
#define OFF_S2H  8454144ull   // 65536
#define OFF_S1O  8519680ull   // 16384
#define OFF_S2O  8536064ull   // 16384
#define OFF_SVAL 8552448ull   // 32*2048
#define OFF_WN   8617984ull   // 32*2048
#define OFF_CHA  8683520ull   // 32*128*65
#define OFF_CHS  8949760ull   // 32*128*65
#define OFF_SIDX 9216000ull   // 32*2048 ints
#define OFF_A    9281536ull   // 32*2049*65
#define OFF_S    13543456ull  // 32*2049*65 -> end 17805376 floats (71.2 MB)

__device__ inline unsigned long long pack_key(float v, int idx) {
    unsigned u = __float_as_uint(v);
    u = (u & 0x80000000u) ? ~u : (u | 0x80000000u);
    return ((unsigned long long)u << 32) | (unsigned)idx;
}
__device__ inline float unpack_key(unsigned long long k) {
    unsigned u = (unsigned)(k >> 32);
    u = (u & 0x80000000u) ? (u ^ 0x80000000u) : ~u;
    return __uint_as_float(u);
}
__device__ inline unsigned long long shfl_xor_u64(unsigned long long x, int mask) {
    unsigned lo = (unsigned)x, hi = (unsigned)(x >> 32);
    lo = (unsigned)__shfl_xor((int)lo, mask, 64);
    hi = (unsigned)__shfl_xor((int)hi, mask, 64);
    return ((unsigned long long)hi << 32) | lo;
}

// ---------------- GEMM 1 + fused s1/s2 projection ----------------
__global__ __launch_bounds__(256) void gemm1_k(const float* __restrict__ X,
                                               const float* __restrict__ Wh,
                                               const float* __restrict__ aH,
                                               float* __restrict__ hh,
                                               float* __restrict__ s1h,
                                               float* __restrict__ s2h) {
    __shared__ float As[64][68];
    __shared__ float Bs[64][68];
    const int tid = threadIdx.x;
    const int bm = blockIdx.x, h = blockIdx.y;
    const int c0 = tid & 63, r0 = tid >> 6;
#pragma unroll
    for (int r = 0; r < 16; ++r) {
        int row = r0 + r * 4;
        As[c0][row] = X[(size_t)(bm * 64 + row) * 64 + c0];
        Bs[row][c0] = Wh[h * 4096 + row * 64 + c0];
    }
    __syncthreads();
    const int tx = tid & 15, ty = tid >> 4;
    const int m0 = ty * 4, n0 = tx * 4;
    float acc[4][4] = {};
#pragma unroll
    for (int kk = 0; kk < 64; ++kk) {
        float4 a = *(const float4*)&As[kk][m0];
        float4 b = *(const float4*)&Bs[kk][n0];
        acc[0][0] += a.x * b.x; acc[0][1] += a.x * b.y; acc[0][2] += a.x * b.z; acc[0][3] += a.x * b.w;
        acc[1][0] += a.y * b.x; acc[1][1] += a.y * b.y; acc[1][2] += a.y * b.z; acc[1][3] += a.y * b.w;
        acc[2][0] += a.z * b.x; acc[2][1] += a.z * b.y; acc[2][2] += a.z * b.z; acc[2][3] += a.z * b.w;
        acc[3][0] += a.w * b.x; acc[3][1] += a.w * b.y; acc[3][2] += a.w * b.z; acc[3][3] += a.w * b.w;
    }
#pragma unroll
    for (int i = 0; i < 4; ++i) {
        float4 v = make_float4(acc[i][0], acc[i][1], acc[i][2], acc[i][3]);
        *(float4*)&hh[(size_t)(bm * 64 + m0 + i) * 256 + h * 64 + n0] = v;
    }
#pragma unroll
    for (int i = 0; i < 4; ++i) {
        float p1 = 0.f, p2 = 0.f;
#pragma unroll
        for (int jj = 0; jj < 4; ++jj) {
            p1 += acc[i][jj] * aH[h * 128 + n0 + jj];
            p2 += acc[i][jj] * aH[h * 128 + 64 + n0 + jj];
        }
#pragma unroll
        for (int off = 8; off; off >>= 1) {
            p1 += __shfl_xor(p1, off, 16);
            p2 += __shfl_xor(p2, off, 16);
        }
        if (tx == 0) {
            s1h[h * NTOT + bm * 64 + m0 + i] = p1;
            s2h[h * NTOT + bm * 64 + m0 + i] = p2;
        }
    }
}

// ---------------- GEMM 2 + fused s1/s2 projection ----------------
__global__ __launch_bounds__(256) void gemm2_k(const float* __restrict__ XC,
                                               const float* __restrict__ Wo,
                                               const float* __restrict__ aO,
                                               float* __restrict__ hc,
                                               float* __restrict__ s1o,
                                               float* __restrict__ s2o) {
    __shared__ float As[64][68];
    __shared__ float Bs[64][68];
    const int tid = threadIdx.x;
    const int bm = blockIdx.x;
    const int c0 = tid & 63, r0 = tid >> 6;
    const int tx = tid & 15, ty = tid >> 4;
    const int m0 = ty * 4, n0 = tx * 4;
    float acc[4][4] = {};
    for (int kt = 0; kt < 4; ++kt) {
#pragma unroll
        for (int r = 0; r < 16; ++r) {
            int row = r0 + r * 4;
            As[c0][row] = XC[(size_t)(bm * 64 + row) * 256 + kt * 64 + c0];
            Bs[row][c0] = Wo[(kt * 64 + row) * 64 + c0];
        }
        __syncthreads();
#pragma unroll
        for (int kk = 0; kk < 64; ++kk) {
            float4 a = *(const float4*)&As[kk][m0];
            float4 b = *(const float4*)&Bs[kk][n0];
            acc[0][0] += a.x * b.x; acc[0][1] += a.x * b.y; acc[0][2] += a.x * b.z; acc[0][3] += a.x * b.w;
            acc[1][0] += a.y * b.x; acc[1][1] += a.y * b.y; acc[1][2] += a.y * b.z; acc[1][3] += a.y * b.w;
            acc[2][0] += a.z * b.x; acc[2][1] += a.z * b.y; acc[2][2] += a.z * b.z; acc[2][3] += a.z * b.w;
            acc[3][0] += a.w * b.x; acc[3][1] += a.w * b.y; acc[3][2] += a.w * b.z; acc[3][3] += a.w * b.w;
        }
        __syncthreads();
    }
#pragma unroll
    for (int i = 0; i < 4; ++i) {
        float4 v = make_float4(acc[i][0], acc[i][1], acc[i][2], acc[i][3]);
        *(float4*)&hc[(size_t)(bm * 64 + m0 + i) * 64 + n0] = v;
    }
#pragma unroll
    for (int i = 0; i < 4; ++i) {
        float p1 = 0.f, p2 = 0.f;
#pragma unroll
        for (int jj = 0; jj < 4; ++jj) {
            p1 += acc[i][jj] * aO[n0 + jj];
            p2 += acc[i][jj] * aO[64 + n0 + jj];
        }
#pragma unroll
        for (int off = 8; off; off >>= 1) {
            p1 += __shfl_xor(p1, off, 16);
            p2 += __shfl_xor(p2, off, 16);
        }
        if (tx == 0) {
            s1o[bm * 64 + m0 + i] = p1;
            s2o[bm * 64 + m0 + i] = p2;
        }
    }
}

// ---------------- fused: bitonic sort + chunk sums + parallel scans; 1 block per task ----------------
__global__ __launch_bounds__(1024) void sortchunkscan_k(const float* __restrict__ s2_all,
                                                        const float* __restrict__ V,
                                                        int heads, int vstride,
                                                        float* __restrict__ g_sval, int* __restrict__ g_sidx,
                                                        float* __restrict__ g_wN,
                                                        float* __restrict__ g_chA, float* __restrict__ g_chS,
                                                        float* __restrict__ g_A, float* __restrict__ g_S) {
    __shared__ unsigned long long sA[1024];
    __shared__ unsigned long long sB[1024];
    __shared__ float chA[8320];
    __shared__ float chS[8320];
    __shared__ float swn[NSEG];
    __shared__ int ssi[NSEG];
    __shared__ float btA[4][65];
    __shared__ float btS[4][65];
    __shared__ float sM2;
    const int tid = threadIdx.x, t = blockIdx.x;
    const int g = t / heads, h = t % heads;
    const float* s2p = s2_all + (size_t)h * NTOT + (size_t)g * NSEG;
    const float* Vp = V + (size_t)g * NSEG * vstride + h * 64;

    unsigned long long a0 = pack_key(s2p[tid], tid);
    unsigned long long a1 = pack_key(s2p[tid + 1024], tid + 1024);
    for (int k = 2; k <= 2048; k <<= 1) {
        const bool up0 = (tid & k) == 0;
        const bool up1 = (((tid + 1024) & k) == 0);
        for (int j = k >> 1; j > 0; j >>= 1) {
            if (j >= 1024) {
                unsigned long long lo = a0 < a1 ? a0 : a1;
                unsigned long long hi = a0 < a1 ? a1 : a0;
                a0 = up0 ? lo : hi;
                a1 = up0 ? hi : lo;
            } else if (j >= 64) {
                __syncthreads();
                sA[tid] = a0; sB[tid] = a1;
                __syncthreads();
                unsigned long long p0 = sA[tid ^ j], p1 = sB[tid ^ j];
                bool lower = (tid & j) == 0;
                a0 = ((a0 < p0) == (lower == up0)) ? a0 : p0;
                a1 = ((a1 < p1) == (lower == up1)) ? a1 : p1;
            } else {
                unsigned long long p0 = shfl_xor_u64(a0, j);
                unsigned long long p1 = shfl_xor_u64(a1, j);
                bool lower = (tid & j) == 0;
                a0 = ((a0 < p0) == (lower == up0)) ? a0 : p0;
                a1 = ((a1 < p1) == (lower == up1)) ? a1 : p1;
            }
        }
    }
    float v0 = unpack_key(a0), v1 = unpack_key(a1);
    if (tid == 1023) sM2 = v1;
    __syncthreads();
    const float M2 = sM2;
    int i0 = (int)(unsigned)(a0 & 0xffffffffu);
    int i1 = (int)(unsigned)(a1 & 0xffffffffu);
    float w0 = __expf(0.2f * (v0 - M2));
    float w1 = __expf(0.2f * (v1 - M2));
    size_t o = (size_t)t * NSEG;
    g_sval[o + tid] = v0; g_sval[o + tid + 1024] = v1;
    g_sidx[o + tid] = i0; g_sidx[o + tid + 1024] = i1;
    g_wN[o + tid] = w0;   g_wN[o + tid + 1024] = w1;
    swn[tid] = w0; swn[tid + 1024] = w1;
    ssi[tid] = i0; ssi[tid + 1024] = i1;
    __syncthreads();
    // chunk sums: wave wv handles chunks 8*wv .. 8*wv+7; lane = dim
    const int wv = tid >> 6, lane = tid & 63;
    for (int cc = 0; cc < 8; ++cc) {
        int c = wv * 8 + cc, base = c * 16;
        float sa = 0.f, swa = 0.f, ss = 0.f, sws = 0.f;
#pragma unroll
        for (int j = 0; j < 16; ++j) {
            float wn = swn[base + j];
            int row = ssi[base + j];
            float v = Vp[(size_t)row * vstride + lane];
            float w2 = wn * wn, wp = w2 * w2 * wn;
            sa += wn * v; swa += wn;
            ss += wp * v; sws += wp;
        }
        chA[c * 65 + lane] = sa; chS[c * 65 + lane] = ss;
        if (lane == 0) { chA[c * 65 + 64] = swa; chS[c * 65 + 64] = sws; }
    }
    __syncthreads();
    // phase 1: per-column scans within 4 blocks of 32 chunks (A: prefix, S: suffix — disjoint threads)
    if (tid < 260) {
        int b = tid / 65, d = tid % 65;
        float run = 0.f;
        for (int c = b * 32; c < b * 32 + 32; ++c) { float v = chA[c * 65 + d]; chA[c * 65 + d] = run; run += v; }
        btA[b][d] = run;
    } else if (tid >= 512 && tid < 772) {
        int u = tid - 512;
        int b = u / 65, d = u % 65;
        float run = 0.f;
        for (int c = b * 32 + 31; c >= b * 32; --c) { run += chS[c * 65 + d]; chS[c * 65 + d] = run; }
        btS[b][d] = run;
    }
    __syncthreads();
    // phase 2: scan the 4 block totals; write boundary table rows
    if (tid < 65) {
        float run = 0.f;
        for (int b = 0; b < 4; ++b) { float v = btA[b][tid]; btA[b][tid] = run; run += v; }
        g_A[(size_t)t * TSTRIDE + (size_t)2048 * TROW + tid] = run;  // k=2048: total
    } else if (tid >= 512 && tid < 577) {
        int d = tid - 512;
        float run = 0.f;
        for (int b = 3; b >= 0; --b) { float v = btS[b][d]; btS[b][d] = run; run += v; }
        g_S[(size_t)t * TSTRIDE + (size_t)2048 * TROW + d] = 0.f;    // k=2048: empty suffix
    }
    __syncthreads();
    // phase 3: add block offsets
    if (tid < 512) {
        for (int i = tid; i < 8320; i += 512) chA[i] += btA[(i / 65) >> 5][i % 65];
    } else {
        for (int i = tid - 512; i < 8320; i += 512) chS[i] += btS[(i / 65) >> 5][i % 65];
    }
    __syncthreads();
    for (int i = tid; i < 8320; i += 1024) {
        g_chA[(size_t)t * 8320 + i] = chA[i];
        g_chS[(size_t)t * 8320 + i] = chS[i];
    }
}

// ---------------- positional prefix/suffix table build: 1 wave per chunk ----------------
__global__ __launch_bounds__(256) void seg_tab_k(const float* __restrict__ V,
                                                 int heads, int vstride,
                                                 const int* __restrict__ g_sidx,
                                                 const float* __restrict__ g_wN,
                                                 const float* __restrict__ g_chA,
                                                 const float* __restrict__ g_chS,
                                                 float* __restrict__ g_A, float* __restrict__ g_S) {
    const int t = blockIdx.y, g = t / heads, h = t % heads;
    const int wv = threadIdx.x >> 6, lane = threadIdx.x & 63;
    const int c = blockIdx.x * 4 + wv;
    const int base = c * 16;
    const float* Vp = V + (size_t)g * NSEG * vstride + h * 64;
    const int* sidx = g_sidx + (size_t)t * NSEG + base;
    const float* wnp = g_wN + (size_t)t * NSEG + base;
    float wn[16], vv[16];
#pragma unroll
    for (int j = 0; j < 16; ++j) wn[j] = wnp[j];
#pragma unroll
    for (int j = 0; j < 16; ++j) vv[j] = Vp[(size_t)sidx[j] * vstride + lane];
    float* A = g_A + (size_t)t * TSTRIDE;
    float* S = g_S + (size_t)t * TSTRIDE;
    float accA = g_chA[((size_t)t * 128 + c) * TROW + lane];
    float scaA = g_chA[((size_t)t * 128 + c) * TROW + 64];
#pragma unroll
    for (int j = 0; j < 16; ++j) {
        size_t pos = base + j;
        A[pos * TROW + lane] = accA;
        if (lane == 0) A[pos * TROW + 64] = scaA;
        accA += wn[j] * vv[j]; scaA += wn[j];
    }
    float accS = 0.f, scaS = 0.f;
    if (c < 127) {
        accS = g_chS[((size_t)t * 128 + c + 1) * TROW + lane];
        scaS = g_chS[((size_t)t * 128 + c + 1) * TROW + 64];
    }
#pragma unroll
    for (int j = 15; j >= 0; --j) {
        float w = wn[j], w2 = w * w, wp = w2 * w2 * w;
        accS += wp * vv[j]; scaS += wp;
        size_t pos = base + j;
        S[pos * TROW + lane] = accS;
        if (lane == 0) S[pos * TROW + 64] = scaS;
    }
}

// ---------------- query: binary search + 2 table-row reads; 16 queries per wave ----------------
template <int MODE>  // 0: ELU -> xc ; 1: ELU + log_softmax -> out
__global__ __launch_bounds__(256) void seg_query_k(const float* __restrict__ s1_all,
                                                   float* __restrict__ out,
                                                   int heads, int ostride,
                                                   const float* __restrict__ g_sval,
                                                   const float* __restrict__ g_A,
                                                   const float* __restrict__ g_S) {
    __shared__ float sval[NSEG];
    const int tid = threadIdx.x;
    const int t = blockIdx.y, g = t / heads, h = t % heads;
    const float4* sv4 = (const float4*)(g_sval + (size_t)t * NSEG);
    for (int i = tid; i < NSEG / 4; i += 256) ((float4*)sval)[i] = sv4[i];
    __syncthreads();
    const float M2 = sval[NSEG - 1];
    const int lane = tid & 63, wv = tid >> 6;
    const int q0 = blockIdx.x * 64 + wv * 16;
    const float* s1p = s1_all + (size_t)h * NTOT + (size_t)g * NSEG;
    float* outp = out + (size_t)g * NSEG * ostride + h * 64;
    const float* A = g_A + (size_t)t * TSTRIDE;
    const float* S = g_S + (size_t)t * TSTRIDE;
    int myq = q0 + (lane & 15);
    float s1v = s1p[myq];
    float th = -s1v;
    int lo = 0, hi = NSEG;
    while (lo < hi) { int mid = (lo + hi) >> 1; if (sval[mid] <= th) lo = mid + 1; else hi = mid; }
    for (int j = 0; j < 16; ++j) {
        int k = __shfl(lo, j, 64);
        float s1q = __shfl(s1v, j, 64);
        const float* rowA = A + (size_t)k * TROW;
        const float* rowS = S + (size_t)k * TROW;
        float accA = rowA[lane], scaA = rowA[64];
        float accS = rowS[lane], scaS = rowS[64];
        float cc = __expf(-0.8f * fmaxf(s1q + M2, 0.f));
        float o = (accS + cc * accA) / (scaS + cc * scaA);
        o = o > 0.f ? o : expm1f(o);  // ELU
        int q = q0 + j;
        if (MODE == 0) {
            outp[(size_t)q * ostride + lane] = o;
        } else {
            float m = o;
#pragma unroll
            for (int off = 32; off; off >>= 1) m = fmaxf(m, __shfl_xor(m, off, 64));
            float e = __expf(o - m);
#pragma unroll
            for (int off = 32; off; off >>= 1) e += __shfl_xor(e, off, 64);
            outp[(size_t)q * ostride + lane] = o - m - __logf(e);
        }
    }
}

extern "C" void kernel_launch(void* const* d_in, const int* in_sizes, int n_in,
                              void* d_out, int out_size, void* d_ws, size_t ws_size,
                              hipStream_t stream) {
    const float* h_states = (const float*)d_in[0];
    const float* W_heads = (const float*)d_in[1];
    const float* a_heads = (const float*)d_in[2];
    const float* W_out = (const float*)d_in[3];
    const float* a_out = (const float*)d_in[4];
    float* w = (float*)d_ws;
    float* hh = w + OFF_HH;
    float* xc = w + OFF_XC;
    float* hc = w + OFF_HH;  // reuse: hh dead after seg_tab (head layer)
    float* s1h = w + OFF_S1H;
    float* s2h = w + OFF_S2H;
    float* s1o = w + OFF_S1O;
    float* s2o = w + OFF_S2O;
    float* g_sval = w + OFF_SVAL;
    float* g_wN = w + OFF_WN;
    float* g_chA = w + OFF_CHA;
    float* g_chS = w + OFF_CHS;
    int* g_sidx = (int*)(w + OFF_SIDX);
    float* g_A = w + OFF_A;
    float* g_S = w + OFF_S;
    float* outp = (float*)d_out;

    gemm1_k<<<dim3(256, 4), 256, 0, stream>>>(h_states, W_heads, a_heads, hh, s1h, s2h);
    sortchunkscan_k<<<32, 1024, 0, stream>>>(s2h, hh, 4, 256, g_sval, g_sidx, g_wN, g_chA, g_chS, g_A, g_S);
    seg_tab_k<<<dim3(32, 32), 256, 0, stream>>>(hh, 4, 256, g_sidx, g_wN, g_chA, g_chS, g_A, g_S);
    seg_query_k<0><<<dim3(32, 32), 256, 0, stream>>>(s1h, xc, 4, 256, g_sval, g_A, g_S);
    gemm2_k<<<256, 256, 0, stream>>>(xc, W_out, a_out, hc, s1o, s2o);
    sortchunkscan_k<<<8, 1024, 0, stream>>>(s2o, hc, 1, 64, g_sval, g_sidx, g_wN, g_chA, g_chS, g_A, g_S);
    seg_tab_k<<<dim3(32, 8), 256, 0, stream>>>(hc, 1, 64, g_sidx, g_wN, g_chA, g_chS, g_A, g_S);
    seg_query_k<1><<<dim3(32, 8), 256, 0, stream>>>(s1o, outp, 1, 64, g_sval, g_A, g_S);
}